// Round 7
// baseline (46.040 us; speedup 1.0000x reference)
//
#include <hip/hip_runtime.h>

typedef float f32x4 __attribute__((ext_vector_type(4)));
typedef int   i32x4 __attribute__((ext_vector_type(4)));

#define KC 512
#define DC 64
#define HWs 4096
#define NPTS 131072
#define NWAVES 16384           // 2 waves per 16-point group (split-K)
#define SE 512.0f              // codebook scale (e' = 512 e, |e'| <= 1)
#define SZ 64.0f               // z scale (z' = 64 z, |z'| < 448)
#define INV_SE 0.001953125f
#define CBASE 8192.0f          // keeps packed scores positive

template <bool HI>
static __device__ inline int pk8(float a, float b, int old) {
    return __builtin_amdgcn_cvt_pk_fp8_f32(a, b, old, HI);
}
template <int S>
static __device__ inline float dec8(int w) {
    return __builtin_amdgcn_cvt_f32_fp8(w, S);
}
static __device__ inline long mk64(int lo, int hi) {
    return (long)(((unsigned long)(unsigned)hi << 32) | (unsigned)lo);
}
static __device__ inline int pack4(float a, float b, float c, float d) {
    int w = pk8<false>(a, b, 0);
    return pk8<true>(c, d, w);
}

// --- prep: codebook -> fp8 (x512, chunk-interleaved) + score init ----------
// thread (r,g) handles dims [8g..8g+7] and [32+8g..32+8g+7] of row r; 16 fp8
// bytes land at cb8[r*16 + g*4] (words) so one ds_read_b128 gives both K-frags.
// score = CBASE - 0.5*SZ*SE*||e||^2 + z'.e'  ->  argmax == true argmin dist.
// 0.5*SZ*SE*||e||^2 = ||e'||^2 * (0.5*64/512) = ss/16.
__global__ __launch_bounds__(256) void vq_prep(const float* __restrict__ cbf,
                                               unsigned int* __restrict__ cb8,
                                               float* __restrict__ inib) {
    int i = blockIdx.x * 256 + threadIdx.x;   // 0..2047
    int r = i >> 2, g = i & 3;
    const float* src = cbf + (size_t)r * DC + 8 * g;
    f32x4 a0 = *(const f32x4*)(src);
    f32x4 a1 = *(const f32x4*)(src + 4);
    f32x4 b0 = *(const f32x4*)(src + 32);
    f32x4 b1 = *(const f32x4*)(src + 36);
    a0 *= SE; a1 *= SE; b0 *= SE; b1 *= SE;
    i32x4 w = {pack4(a0[0], a0[1], a0[2], a0[3]),
               pack4(a1[0], a1[1], a1[2], a1[3]),
               pack4(b0[0], b0[1], b0[2], b0[3]),
               pack4(b1[0], b1[1], b1[2], b1[3])};
    *(i32x4*)(cb8 + (size_t)i * 4) = w;
    float ss = 0.f;
#pragma unroll
    for (int j = 0; j < 4; ++j) {
        ss = fmaf(a0[j], a0[j], ss); ss = fmaf(a1[j], a1[j], ss);
        ss = fmaf(b0[j], b0[j], ss); ss = fmaf(b1[j], b1[j], ss);
    }
    ss += __shfl_xor(ss, 1, 64);
    ss += __shfl_xor(ss, 2, 64);              // row sum over the 4 chunks
    if (g == 0) inib[r] = CBASE - 0.0625f * ss;
}

// --- main: LDS fp8 codebook, split-K wave pairs, packed argmax -------------
__global__ __launch_bounds__(512, 8) void vq_search(const float* __restrict__ z,
                                                    const unsigned int* __restrict__ cb8,
                                                    const float* __restrict__ inib,
                                                    float* __restrict__ outq,
                                                    float* __restrict__ partial) {
    __shared__ unsigned int cbL[KC * 16];     // 32 KB fp8 codebook image
    __shared__ float iniL[KC];                // 2 KB score inits
    __shared__ unsigned int combL[128];       // pair-combine scratch
    const int tid = threadIdx.x;

    // stage 34 KB global -> LDS
    {
        const i32x4* srcv = (const i32x4*)cb8;
        i32x4* dstv = (i32x4*)cbL;
#pragma unroll
        for (int q = 0; q < 4; ++q) dstv[tid + q * 512] = srcv[tid + q * 512];
        iniL[tid] = inib[tid];
    }
    __syncthreads();

    const int lane = tid & 63, wid = tid >> 6;     // 8 waves = 4 pairs
    const int pair = wid >> 1, p = wid & 1;        // p: codebook half
    const int pg = blockIdx.x * 4 + pair;          // 16-point group, 0..8191
    const int p0 = pg * 16;
    const int b  = p0 >> 12;                       // 16 | 4096 -> same b
    const int g  = lane >> 4, pl = lane & 15;
    const int s0 = (p0 & (HWs - 1)) + pl;
    const float* zbase = z + (size_t)b * (DC * HWs) + s0;

    // z: fp32 regs (for loss/epilogue) + fp8 B-frags (scaled by SZ)
    float zt[16];
#pragma unroll
    for (int j = 0; j < 8; ++j) {
        zt[j]     = zbase[(size_t)(8 * g + j) * HWs];
        zt[8 + j] = zbase[(size_t)(32 + 8 * g + j) * HWs];
    }
    const long zfr0 = mk64(pack4(SZ * zt[0],  SZ * zt[1],  SZ * zt[2],  SZ * zt[3]),
                           pack4(SZ * zt[4],  SZ * zt[5],  SZ * zt[6],  SZ * zt[7]));
    const long zfr1 = mk64(pack4(SZ * zt[8],  SZ * zt[9],  SZ * zt[10], SZ * zt[11]),
                           pack4(SZ * zt[12], SZ * zt[13], SZ * zt[14], SZ * zt[15]));

    // scan this wave's half of the codebook (16 tiles of 16 codes)
    unsigned best = 0u;
    const int ko = p * 256;
#pragma unroll 4
    for (int t = 0; t < 16; ++t) {
        i32x4 aw = *(const i32x4*)(cbL + (size_t)(ko + 16 * t + pl) * 16 + g * 4);
        long A0 = mk64(aw[0], aw[1]);          // dims 8g..8g+7
        long A1 = mk64(aw[2], aw[3]);          // dims 32+8g..32+8g+7
        f32x4 acc = *(const f32x4*)(iniL + ko + 16 * t + 4 * g);
        acc = __builtin_amdgcn_mfma_f32_16x16x32_fp8_fp8(A0, zfr0, acc, 0, 0, 0);
        acc = __builtin_amdgcn_mfma_f32_16x16x32_fp8_fp8(A1, zfr1, acc, 0, 0, 0);
#pragma unroll
        for (int j = 0; j < 4; ++j) {
            unsigned u = __builtin_bit_cast(unsigned, acc[j])
                       | (unsigned)(ko + 16 * t + 4 * g + j);
            best = best > u ? best : u;
        }
    }

    // in-wave argmax across the 4 g-groups
#pragma unroll
    for (int m = 16; m <= 32; m <<= 1) {
        unsigned o = (unsigned)__shfl_xor((int)best, m, 64);
        best = best > o ? best : o;
    }

    // cross-wave combine within the pair
    if (lane < 16) combL[wid * 16 + lane] = best;
    __syncthreads();
    {
        unsigned o = combL[(wid ^ 1) * 16 + pl];
        best = best > o ? best : o;
    }
    const int bidx = best & 511;

    // epilogue: wave p handles dims [32p, 32p+32); decode code from LDS
    const unsigned int* qw = cbL + (size_t)bidx * 16 + g * 4 + 2 * p;
    const int w0 = (int)qw[0], w1 = (int)qw[1];
    float qv[8];
    qv[0] = dec8<0>(w0) * INV_SE; qv[1] = dec8<1>(w0) * INV_SE;
    qv[2] = dec8<2>(w0) * INV_SE; qv[3] = dec8<3>(w0) * INV_SE;
    qv[4] = dec8<0>(w1) * INV_SE; qv[5] = dec8<1>(w1) * INV_SE;
    qv[6] = dec8<2>(w1) * INV_SE; qv[7] = dec8<3>(w1) * INV_SE;

    float* obase = outq + (size_t)b * (DC * HWs) + s0;
    float err = 0.f;
#pragma unroll
    for (int j = 0; j < 8; ++j) {
        size_t o = (size_t)(32 * p + 8 * g + j) * HWs;
        float d = qv[j] - zt[8 * p + j];
        obase[o] = qv[j];
        err = fmaf(d, d, err);
    }

#pragma unroll
    for (int off = 32; off; off >>= 1) err += __shfl_down(err, off, 64);
    if (lane == 0) partial[blockIdx.x * 8 + wid] = err;
}

// --- final loss reduction ---------------------------------------------------
__global__ __launch_bounds__(256) void vq_loss(const float* __restrict__ partial,
                                               float* __restrict__ loss_out) {
    float s = 0.f;
    for (int i = threadIdx.x; i < NWAVES; i += 256) s += partial[i];
#pragma unroll
    for (int off = 32; off; off >>= 1) s += __shfl_down(s, off, 64);
    __shared__ float red[4];
    if ((threadIdx.x & 63) == 0) red[threadIdx.x >> 6] = s;
    __syncthreads();
    if (threadIdx.x == 0)
        loss_out[0] = 1.25f * ((red[0] + red[1]) + (red[2] + red[3])) / 8388608.0f;
}

extern "C" void kernel_launch(void* const* d_in, const int* in_sizes, int n_in,
                              void* d_out, int out_size, void* d_ws, size_t ws_size,
                              hipStream_t stream) {
    const float* z   = (const float*)d_in[0];    // [32,64,64,64] f32
    const float* cbf = (const float*)d_in[1];    // [512,64] f32
    float* outq = (float*)d_out;                 // 8388608 + 1 (loss)
    float* loss = outq + 8388608;

    unsigned int* cb8 = (unsigned int*)d_ws;                   // 32 KB
    float* inib    = (float*)((char*)d_ws + 32768);            // 2 KB
    float* partial = (float*)((char*)d_ws + 32768 + 2048);     // 64 KB

    vq_prep<<<8, 256, 0, stream>>>(cbf, cb8, inib);
    vq_search<<<2048, 512, 0, stream>>>(z, cb8, inib, outq, partial);
    vq_loss<<<1, 256, 0, stream>>>(partial, loss);
}

// Round 8
// 24.156 us; speedup vs baseline: 1.9060x; 1.9060x over previous
//
#include <hip/hip_runtime.h>

typedef float f32x4 __attribute__((ext_vector_type(4)));
typedef int   i32x4 __attribute__((ext_vector_type(4)));

#define KC 512
#define DC 64
#define HWs 4096
#define NPTS 131072
#define NGRP 4096              // 32 points per wave
#define SE 512.0f              // codebook scale (e' = 512 e)
#define SZ 64.0f               // z scale (z' = 64 z)
#define CBASE 4096.0f          // keeps packed scores positive

template <bool HI>
static __device__ inline int pk8(float a, float b, int old) {
    return __builtin_amdgcn_cvt_pk_fp8_f32(a, b, old, HI);
}
static __device__ inline long mk64(int lo, int hi) {
    return (long)(((unsigned long)(unsigned)hi << 32) | (unsigned)lo);
}
static __device__ inline int pack4(float a, float b, float c, float d) {
    int w = pk8<false>(a, b, 0);
    return pk8<true>(c, d, w);
}

// --- main: in-block fp8 codebook staging, MFMA search, packed argmax -------
// score = CBASE - 0.5*SZ*SE*||e||^2 + z'.e'  (argmax == argmin distance)
// norm term folded into a 3rd MFMA: A byte0 (g==0 lanes) = fp8(-ss/16),
// B byte0 = fp8(1.0); C input = CBASE broadcast.
__global__ __launch_bounds__(512, 4) void vq_search(const float* __restrict__ z,
                                                    const float* __restrict__ cbf,
                                                    float* __restrict__ outq,
                                                    float* __restrict__ partial) {
    __shared__ unsigned int cbL[KC * 16];   // 32 KB fp8 codebook image
    __shared__ unsigned int iniT[128];      // 512 ini bytes, [pl][t] transposed
    const int tid = threadIdx.x;

    // ---- stage: fp32 codebook -> fp8 LDS (x512), ini bytes (4 thr/row) ----
#pragma unroll
    for (int pass = 0; pass < 4; ++pass) {
        const int i = pass * 512 + tid;          // 0..2047
        const int r = i >> 2, c = i & 3;
        const float* src = cbf + (size_t)r * DC + 8 * c;
        f32x4 a0 = *(const f32x4*)(src);
        f32x4 a1 = *(const f32x4*)(src + 4);
        f32x4 b0 = *(const f32x4*)(src + 32);
        f32x4 b1 = *(const f32x4*)(src + 36);
        a0 *= SE; a1 *= SE; b0 *= SE; b1 *= SE;
        i32x4 w = {pack4(a0[0], a0[1], a0[2], a0[3]),
                   pack4(a1[0], a1[1], a1[2], a1[3]),
                   pack4(b0[0], b0[1], b0[2], b0[3]),
                   pack4(b1[0], b1[1], b1[2], b1[3])};
        *(i32x4*)(cbL + (size_t)r * 16 + c * 4) = w;
        float ss = 0.f;
#pragma unroll
        for (int j = 0; j < 4; ++j) {
            ss = fmaf(a0[j], a0[j], ss); ss = fmaf(a1[j], a1[j], ss);
            ss = fmaf(b0[j], b0[j], ss); ss = fmaf(b1[j], b1[j], ss);
        }
        ss += __shfl_xor(ss, 1, 64);
        ss += __shfl_xor(ss, 2, 64);             // row sum over 4 chunks
        if (c == 0) {
            int w8 = pk8<false>(-0.0625f * ss, 0.f, 0);
            ((unsigned char*)iniT)[(r & 15) * 32 + (r >> 4)] = (unsigned char)(w8 & 0xff);
        }
    }
    __syncthreads();

    const int lane = tid & 63, wid = tid >> 6;
    const int wg = blockIdx.x * 8 + wid;         // 0..4095
    const int p0 = wg * 32;
    const int b  = p0 >> 12;                     // 32 | 4096 -> same b
    const int g  = lane >> 4, pl = lane & 15;
    const int s0 = (p0 & (HWs - 1)) + pl;
    const float* zbase = z + (size_t)b * (DC * HWs) + s0;

    // z: 2 points (pl, pl+16) x 16 dims; fp32 in regs + scaled fp8 B-frags
    float zt[32];
#pragma unroll
    for (int j = 0; j < 8; ++j) {
        zt[j]      = zbase[(size_t)(8 * g + j) * HWs];
        zt[8 + j]  = zbase[(size_t)(32 + 8 * g + j) * HWs];
        zt[16 + j] = zbase[(size_t)(8 * g + j) * HWs + 16];
        zt[24 + j] = zbase[(size_t)(32 + 8 * g + j) * HWs + 16];
    }
    const long zA0 = mk64(pack4(SZ * zt[0],  SZ * zt[1],  SZ * zt[2],  SZ * zt[3]),
                          pack4(SZ * zt[4],  SZ * zt[5],  SZ * zt[6],  SZ * zt[7]));
    const long zA1 = mk64(pack4(SZ * zt[8],  SZ * zt[9],  SZ * zt[10], SZ * zt[11]),
                          pack4(SZ * zt[12], SZ * zt[13], SZ * zt[14], SZ * zt[15]));
    const long zB0 = mk64(pack4(SZ * zt[16], SZ * zt[17], SZ * zt[18], SZ * zt[19]),
                          pack4(SZ * zt[20], SZ * zt[21], SZ * zt[22], SZ * zt[23]));
    const long zB1 = mk64(pack4(SZ * zt[24], SZ * zt[25], SZ * zt[26], SZ * zt[27]),
                          pack4(SZ * zt[28], SZ * zt[29], SZ * zt[30], SZ * zt[31]));

    // per-lane ini bytes for codes 16t+pl, t=0..31 (transposed rows)
    const i32x4 iw0 = *(const i32x4*)((const char*)iniT + pl * 32);
    const i32x4 iw1 = *(const i32x4*)((const char*)iniT + pl * 32 + 16);
    const unsigned gmask = (g == 0) ? 0xffu : 0u;
    const long bunit = (g == 0) ? 0x38L : 0L;    // fp8 1.0 at k=0
    const f32x4 cb4 = {CBASE, CBASE, CBASE, CBASE};

    unsigned best0 = 0u, best1 = 0u;
#pragma unroll
    for (int t = 0; t < 32; ++t) {
        const unsigned wrd = (t < 16) ? (unsigned)iw0[(t >> 2) & 3]
                                      : (unsigned)iw1[((t - 16) >> 2) & 3];
        const long a_ini = (long)((wrd >> ((t & 3) * 8)) & gmask);
        i32x4 aw = *(const i32x4*)(cbL + (size_t)(16 * t + pl) * 16 + g * 4);
        long A0 = mk64(aw[0], aw[1]);            // dims 8g..8g+7
        long A1 = mk64(aw[2], aw[3]);            // dims 32+8g..32+8g+7
        f32x4 ia = __builtin_amdgcn_mfma_f32_16x16x32_fp8_fp8(a_ini, bunit, cb4, 0, 0, 0);
        f32x4 acc0 = __builtin_amdgcn_mfma_f32_16x16x32_fp8_fp8(A0, zA0, ia, 0, 0, 0);
        acc0 = __builtin_amdgcn_mfma_f32_16x16x32_fp8_fp8(A1, zA1, acc0, 0, 0, 0);
        f32x4 acc1 = __builtin_amdgcn_mfma_f32_16x16x32_fp8_fp8(A0, zB0, ia, 0, 0, 0);
        acc1 = __builtin_amdgcn_mfma_f32_16x16x32_fp8_fp8(A1, zB1, acc1, 0, 0, 0);
#pragma unroll
        for (int j = 0; j < 4; ++j) {
            const unsigned code = (unsigned)(16 * t + 4 * g + j);
            unsigned u0 = __builtin_bit_cast(unsigned, acc0[j]) | code;
            unsigned u1 = __builtin_bit_cast(unsigned, acc1[j]) | code;
            best0 = best0 > u0 ? best0 : u0;
            best1 = best1 > u1 ? best1 : u1;
        }
    }

    // argmax across the 4 g-groups holding the same point
#pragma unroll
    for (int m = 16; m <= 32; m <<= 1) {
        unsigned o0 = (unsigned)__shfl_xor((int)best0, m, 64);
        unsigned o1 = (unsigned)__shfl_xor((int)best1, m, 64);
        best0 = best0 > o0 ? best0 : o0;
        best1 = best1 > o1 ? best1 : o1;
    }
    const int bidx0 = best0 & 511, bidx1 = best1 & 511;

    // epilogue: gather exact fp32 code rows (L2-hot), write out, loss
    float err = 0.f;
    float* obase = outq + (size_t)b * (DC * HWs) + s0;
    {
        const float* qp = cbf + (size_t)bidx0 * DC + 8 * g;
        f32x4 q0 = *(const f32x4*)(qp);
        f32x4 q1 = *(const f32x4*)(qp + 4);
        f32x4 q2 = *(const f32x4*)(qp + 32);
        f32x4 q3 = *(const f32x4*)(qp + 36);
#pragma unroll
        for (int j = 0; j < 4; ++j) {
            size_t o0_ = (size_t)(8 * g + j) * HWs;
            size_t o1_ = (size_t)(8 * g + 4 + j) * HWs;
            size_t o2_ = (size_t)(32 + 8 * g + j) * HWs;
            size_t o3_ = (size_t)(32 + 8 * g + 4 + j) * HWs;
            obase[o0_] = q0[j]; float d0 = q0[j] - zt[j];      err = fmaf(d0, d0, err);
            obase[o1_] = q1[j]; float d1 = q1[j] - zt[4 + j];  err = fmaf(d1, d1, err);
            obase[o2_] = q2[j]; float d2 = q2[j] - zt[8 + j];  err = fmaf(d2, d2, err);
            obase[o3_] = q3[j]; float d3 = q3[j] - zt[12 + j]; err = fmaf(d3, d3, err);
        }
    }
    {
        const float* qp = cbf + (size_t)bidx1 * DC + 8 * g;
        f32x4 q0 = *(const f32x4*)(qp);
        f32x4 q1 = *(const f32x4*)(qp + 4);
        f32x4 q2 = *(const f32x4*)(qp + 32);
        f32x4 q3 = *(const f32x4*)(qp + 36);
#pragma unroll
        for (int j = 0; j < 4; ++j) {
            size_t o0_ = (size_t)(8 * g + j) * HWs + 16;
            size_t o1_ = (size_t)(8 * g + 4 + j) * HWs + 16;
            size_t o2_ = (size_t)(32 + 8 * g + j) * HWs + 16;
            size_t o3_ = (size_t)(32 + 8 * g + 4 + j) * HWs + 16;
            obase[o0_] = q0[j]; float d0 = q0[j] - zt[16 + j]; err = fmaf(d0, d0, err);
            obase[o1_] = q1[j]; float d1 = q1[j] - zt[20 + j]; err = fmaf(d1, d1, err);
            obase[o2_] = q2[j]; float d2 = q2[j] - zt[24 + j]; err = fmaf(d2, d2, err);
            obase[o3_] = q3[j]; float d3 = q3[j] - zt[28 + j]; err = fmaf(d3, d3, err);
        }
    }

#pragma unroll
    for (int off = 32; off; off >>= 1) err += __shfl_down(err, off, 64);
    if (lane == 0) partial[wg] = err;
}

// --- final loss reduction ---------------------------------------------------
__global__ __launch_bounds__(256) void vq_loss(const float* __restrict__ partial,
                                               float* __restrict__ loss_out) {
    float s = 0.f;
#pragma unroll
    for (int q = 0; q < NGRP / 256; ++q) s += partial[q * 256 + threadIdx.x];
#pragma unroll
    for (int off = 32; off; off >>= 1) s += __shfl_down(s, off, 64);
    __shared__ float red[4];
    if ((threadIdx.x & 63) == 0) red[threadIdx.x >> 6] = s;
    __syncthreads();
    if (threadIdx.x == 0)
        loss_out[0] = 1.25f * ((red[0] + red[1]) + (red[2] + red[3])) / 8388608.0f;
}

extern "C" void kernel_launch(void* const* d_in, const int* in_sizes, int n_in,
                              void* d_out, int out_size, void* d_ws, size_t ws_size,
                              hipStream_t stream) {
    const float* z   = (const float*)d_in[0];    // [32,64,64,64] f32
    const float* cbf = (const float*)d_in[1];    // [512,64] f32
    float* outq = (float*)d_out;                 // 8388608 + 1 (loss)
    float* loss = outq + 8388608;
    float* partial = (float*)d_ws;               // 4096 f32

    vq_search<<<NGRP / 8, 512, 0, stream>>>(z, cbf, outq, partial);
    vq_loss<<<1, 256, 0, stream>>>(partial, loss);
}